// Round 1
// baseline (596.797 us; speedup 1.0000x reference)
//
#include <hip/hip_runtime.h>
#include <hip/hip_bf16.h>

namespace {

constexpr int Bc = 4, Hc = 16, Sc = 2048, Dc = 64;

using bf16x8 = __attribute__((ext_vector_type(8))) __bf16;
using f32x4  = __attribute__((ext_vector_type(4))) float;

__device__ __forceinline__ __bf16 f2bf(float f) {
  unsigned u = __builtin_bit_cast(unsigned, f);
  unsigned r = u + 0x7fffu + ((u >> 16) & 1u);  // RNE
  unsigned short h = (unsigned short)(r >> 16);
  return __builtin_bit_cast(__bf16, h);
}

// 4 waves/block; wave w owns q-rows [blockIdx.x*64 + w*16, +16).
// Per KV-block of 32: QK^T (4 mfma) -> online softmax -> P via LDS transpose -> PV (4 mfma).
__global__ __launch_bounds__(256, 4)
void fattn_kernel(const float* __restrict__ Q, const float* __restrict__ K,
                  const float* __restrict__ V, float* __restrict__ O) {
  const int wid  = threadIdx.x >> 6;
  const int lane = threadIdx.x & 63;
  const int r = lane & 15;   // frag row/col index
  const int g = lane >> 4;   // 4-lane-group id 0..3

  const int bh  = blockIdx.y;
  const int wqb = blockIdx.x * 64 + wid * 16;

  const size_t base = (size_t)bh * Sc * Dc;
  const float* Qb = Q + base;
  const float* Kb = K + base;
  const float* Vb = V + base;
  float*       Ob = O + base;

  // Q fragments: lane holds row r, d = s*32 + g*8 + j.  Scale 1/8 folded in (exact in bf16).
  bf16x8 qf[2];
  #pragma unroll
  for (int s = 0; s < 2; ++s) {
    const float* src = Qb + (size_t)(wqb + r) * Dc + s * 32 + g * 8;
    f32x4 a0 = *reinterpret_cast<const f32x4*>(src);
    f32x4 a1 = *reinterpret_cast<const f32x4*>(src + 4);
    #pragma unroll
    for (int j = 0; j < 4; ++j) { qf[s][j] = f2bf(a0[j] * 0.125f); qf[s][4 + j] = f2bf(a1[j] * 0.125f); }
  }

  f32x4 o_acc[4];   // dsub 0..3 (d = dsub*16 + r), reg t = q-sub (q = wqb + g*4 + t)
  #pragma unroll
  for (int t = 0; t < 4; ++t) o_acc[t] = f32x4{0.f, 0.f, 0.f, 0.f};
  float m_i[4], l_i[4];
  #pragma unroll
  for (int t = 0; t < 4; ++t) { m_i[t] = -1e30f; l_i[t] = 0.f; }

  // per-wave P transpose buffer; stride 40 shorts (80 B) keeps b128 reads ~conflict-free
  __shared__ __align__(16) __bf16 p_lds[4][16][40];

  const int nkb = (wqb + 15) / 32 + 1;  // causal: only blocks touching the lower triangle
  for (int kb = 0; kb < nkb; ++kb) {
    const int kbase = kb * 32;

    // ---- QK^T: S[q, kbase + ks*16 + col] ----
    f32x4 sacc[2];
    sacc[0] = f32x4{0.f, 0.f, 0.f, 0.f};
    sacc[1] = f32x4{0.f, 0.f, 0.f, 0.f};
    #pragma unroll
    for (int ks = 0; ks < 2; ++ks) {
      #pragma unroll
      for (int s = 0; s < 2; ++s) {
        const float* src = Kb + (size_t)(kbase + ks * 16 + r) * Dc + s * 32 + g * 8;
        f32x4 a0 = *reinterpret_cast<const f32x4*>(src);
        f32x4 a1 = *reinterpret_cast<const f32x4*>(src + 4);
        bf16x8 kf;
        #pragma unroll
        for (int j = 0; j < 4; ++j) { kf[j] = f2bf(a0[j]); kf[4 + j] = f2bf(a1[j]); }
        sacc[ks] = __builtin_amdgcn_mfma_f32_16x16x32_bf16(qf[s], kf, sacc[ks], 0, 0, 0);
      }
    }

    // ---- online softmax (D-layout: q = wqb + g*4 + t, k = kbase + ks*16 + r) ----
    float p0v[4], p1v[4];
    #pragma unroll
    for (int t = 0; t < 4; ++t) {
      const int qg = wqb + g * 4 + t;
      float s0 = (kbase + r      <= qg) ? sacc[0][t] : -1e30f;
      float s1 = (kbase + 16 + r <= qg) ? sacc[1][t] : -1e30f;
      float mx = fmaxf(s0, s1);
      #pragma unroll
      for (int sh = 1; sh < 16; sh <<= 1) mx = fmaxf(mx, __shfl_xor(mx, sh));
      const float m_new = fmaxf(m_i[t], mx);
      const float corr  = __expf(m_i[t] - m_new);
      const float p0 = __expf(s0 - m_new);
      const float p1 = __expf(s1 - m_new);
      float rs = p0 + p1;
      #pragma unroll
      for (int sh = 1; sh < 16; sh <<= 1) rs += __shfl_xor(rs, sh);
      l_i[t] = l_i[t] * corr + rs;
      m_i[t] = m_new;
      #pragma unroll
      for (int dsub = 0; dsub < 4; ++dsub) o_acc[dsub][t] *= corr;
      p0v[t] = p0; p1v[t] = p1;
    }

    // ---- P -> LDS (D-layout) -> A-fragment layout ----
    #pragma unroll
    for (int t = 0; t < 4; ++t) {
      p_lds[wid][g * 4 + t][r]      = f2bf(p0v[t]);
      p_lds[wid][g * 4 + t][16 + r] = f2bf(p1v[t]);
    }
    asm volatile("s_waitcnt lgkmcnt(0)" ::: "memory");  // wave-internal write->read fence
    bf16x8 pf = *reinterpret_cast<const bf16x8*>(&p_lds[wid][r][g * 8]);

    // ---- PV: O[q, dsub*16 + r] += P[q, k] * V[kbase + k][d] ----
    #pragma unroll
    for (int dsub = 0; dsub < 4; ++dsub) {
      const float* src = Vb + (size_t)(kbase + g * 8) * Dc + dsub * 16 + r;
      bf16x8 vf;
      #pragma unroll
      for (int j = 0; j < 8; ++j) vf[j] = f2bf(src[(size_t)j * Dc]);
      o_acc[dsub] = __builtin_amdgcn_mfma_f32_16x16x32_bf16(pf, vf, o_acc[dsub], 0, 0, 0);
    }
    asm volatile("" ::: "memory");  // keep next iter's LDS writes after this iter's read
  }

  // ---- epilogue ----
  #pragma unroll
  for (int t = 0; t < 4; ++t) {
    const float inv = 1.0f / l_i[t];
    float* dst = Ob + (size_t)(wqb + g * 4 + t) * Dc;
    #pragma unroll
    for (int dsub = 0; dsub < 4; ++dsub) dst[dsub * 16 + r] = o_acc[dsub][t] * inv;
  }
}

}  // namespace

extern "C" void kernel_launch(void* const* d_in, const int* in_sizes, int n_in,
                              void* d_out, int out_size, void* d_ws, size_t ws_size,
                              hipStream_t stream) {
  const float* q = (const float*)d_in[0];
  const float* k = (const float*)d_in[1];
  const float* v = (const float*)d_in[2];
  // d_in[3] is the triu mask; causality is applied analytically.
  float* o = (float*)d_out;
  dim3 grid(Sc / 64, Bc * Hc);
  fattn_kernel<<<grid, dim3(256), 0, stream>>>(q, k, v, o);
}

// Round 2
// 238.251 us; speedup vs baseline: 2.5049x; 2.5049x over previous
//
#include <hip/hip_runtime.h>
#include <hip/hip_bf16.h>

namespace {

constexpr int Bc = 4, Hc = 16, Sc = 2048, Dc = 64;

using bf16x4 = __attribute__((ext_vector_type(4))) __bf16;
using bf16x8 = __attribute__((ext_vector_type(8))) __bf16;
using f32x4  = __attribute__((ext_vector_type(4))) float;

__device__ __forceinline__ __bf16 c2bf(float f) { return (__bf16)f; }

// bank-spreading swizzle for the transposed V tile: a pure function of d,
// chosen so the per-write-instruction variation of d lands in LDS bank bits.
__device__ __forceinline__ int vswz(int d) { return ((d >> 2) ^ d) & 7; }

// Block = 64 q-rows, 4 waves (16 q-rows each). KV staged cooperatively in
// 64-row tiles as bf16: K row-major (XOR-swizzled), V transposed (swizzled).
__global__ __launch_bounds__(256, 4)
void fattn_kernel(const float* __restrict__ Q, const float* __restrict__ K,
                  const float* __restrict__ V, float* __restrict__ O) {
  const int tid  = threadIdx.x;
  const int wid  = tid >> 6;
  const int lane = tid & 63;
  const int r    = lane & 15;   // fragment row/col
  const int g    = lane >> 4;   // 16-lane group 0..3

  const int qb   = blockIdx.x * 64;
  const int wqb  = qb + wid * 16;

  const size_t base = (size_t)blockIdx.y * Sc * Dc;
  const float* Qb = Q + base;
  const float* Kb = K + base;
  const float* Vb = V + base;
  float*       Ob = O + base;

  __shared__ __align__(16) __bf16 k_lds[64][64];   // K[k][d], col ^= (row&7)<<3
  __shared__ __align__(16) __bf16 vt_lds[64][64];  // V^T[d][k], k ^= vswz(d)<<3
  __shared__ __align__(16) __bf16 p_lds[4][16][72];

  // Q fragment: lane holds q-row (wqb + r), d = s*32 + g*8 + j.  1/8 scale folded in.
  bf16x8 qf[2];
  #pragma unroll
  for (int s = 0; s < 2; ++s) {
    const float* src = Qb + (size_t)(wqb + r) * Dc + s * 32 + g * 8;
    f32x4 a0 = *(const f32x4*)src;
    f32x4 a1 = *(const f32x4*)(src + 4);
    #pragma unroll
    for (int j = 0; j < 4; ++j) { qf[s][j] = c2bf(a0[j] * 0.125f); qf[s][4 + j] = c2bf(a1[j] * 0.125f); }
  }

  f32x4 o_acc[4];   // [dsub], reg t -> q = wqb + g*4 + t, d = dsub*16 + r
  #pragma unroll
  for (int d = 0; d < 4; ++d) o_acc[d] = f32x4{0.f, 0.f, 0.f, 0.f};
  float m_i[4], l_i[4];
  #pragma unroll
  for (int t = 0; t < 4; ++t) { m_i[t] = -1e30f; l_i[t] = 0.f; }

  const int sr0 = tid >> 4;          // staging: row within 16-row slab
  const int sc  = (tid & 15) * 4;    // staging: 4-float column chunk
  const int h8r = (r & 7) << 3;

  const int nkb = blockIdx.x + 1;    // causal tile bound
  for (int kb = 0; kb < nkb; ++kb) {
    const int kbase = kb * 64;

    // ---- cooperative staging: 4 slabs of 16 rows; 16B/lane coalesced ----
    #pragma unroll
    for (int L = 0; L < 4; ++L) {
      const int row = L * 16 + sr0;
      const float* ksrc = Kb + (size_t)(kbase + row) * Dc + sc;
      const float* vsrc = Vb + (size_t)(kbase + row) * Dc + sc;
      f32x4 kx = *(const f32x4*)ksrc;
      f32x4 vx = *(const f32x4*)vsrc;
      bf16x4 kq = { c2bf(kx[0]), c2bf(kx[1]), c2bf(kx[2]), c2bf(kx[3]) };
      *(bf16x4*)&k_lds[row][sc ^ ((row & 7) << 3)] = kq;
      #pragma unroll
      for (int i = 0; i < 4; ++i) {
        const int d = sc + i;
        vt_lds[d][row ^ (vswz(d) << 3)] = c2bf(vx[i]);
      }
    }
    __syncthreads();

    // ---- QK^T: sacc[ks], D-layout q = g*4+t, k = kbase + ks*16 + r ----
    f32x4 sacc[4];
    #pragma unroll
    for (int ks = 0; ks < 4; ++ks) sacc[ks] = f32x4{0.f, 0.f, 0.f, 0.f};
    #pragma unroll
    for (int ks = 0; ks < 4; ++ks) {
      #pragma unroll
      for (int s = 0; s < 2; ++s) {
        bf16x8 kf = *(const bf16x8*)&k_lds[ks * 16 + r][(s * 32 + g * 8) ^ h8r];
        sacc[ks] = __builtin_amdgcn_mfma_f32_16x16x32_bf16(qf[s], kf, sacc[ks], 0, 0, 0);
      }
    }

    // ---- online softmax over 64 k-columns ----
    const bool notfull = (kbase + 63 > wqb);  // wave-uniform: only diagonal tile masks
    #pragma unroll
    for (int t = 0; t < 4; ++t) {
      const int qg = wqb + g * 4 + t;
      float sv0 = sacc[0][t], sv1 = sacc[1][t], sv2 = sacc[2][t], sv3 = sacc[3][t];
      if (notfull) {
        if (kbase      + r > qg) sv0 = -1e30f;
        if (kbase + 16 + r > qg) sv1 = -1e30f;
        if (kbase + 32 + r > qg) sv2 = -1e30f;
        if (kbase + 48 + r > qg) sv3 = -1e30f;
      }
      float mx = fmaxf(fmaxf(sv0, sv1), fmaxf(sv2, sv3));
      mx = fmaxf(mx, __shfl_xor(mx, 1));
      mx = fmaxf(mx, __shfl_xor(mx, 2));
      mx = fmaxf(mx, __shfl_xor(mx, 4));
      mx = fmaxf(mx, __shfl_xor(mx, 8));
      const float m_new = fmaxf(m_i[t], mx);
      const float corr  = __expf(m_i[t] - m_new);
      const float p0 = __expf(sv0 - m_new);
      const float p1 = __expf(sv1 - m_new);
      const float p2 = __expf(sv2 - m_new);
      const float p3 = __expf(sv3 - m_new);
      float rs = (p0 + p1) + (p2 + p3);
      rs += __shfl_xor(rs, 1);
      rs += __shfl_xor(rs, 2);
      rs += __shfl_xor(rs, 4);
      rs += __shfl_xor(rs, 8);
      l_i[t] = l_i[t] * corr + rs;
      m_i[t] = m_new;
      #pragma unroll
      for (int d = 0; d < 4; ++d) o_acc[d][t] *= corr;
      __bf16* pr = &p_lds[wid][g * 4 + t][0];
      pr[r]      = c2bf(p0);
      pr[16 + r] = c2bf(p1);
      pr[32 + r] = c2bf(p2);
      pr[48 + r] = c2bf(p3);
    }
    asm volatile("s_waitcnt lgkmcnt(0)" ::: "memory");  // wave-internal P write->read fence

    // ---- PV: A = P (via p_lds transpose), B = V^T tile reads ----
    bf16x8 pf0 = *(const bf16x8*)&p_lds[wid][r][g * 8];
    bf16x8 pf1 = *(const bf16x8*)&p_lds[wid][r][32 + g * 8];
    #pragma unroll
    for (int ds = 0; ds < 4; ++ds) {
      const int d  = ds * 16 + r;
      const int fs = vswz(d) << 3;
      bf16x8 v0 = *(const bf16x8*)&vt_lds[d][(g * 8) ^ fs];
      bf16x8 v1 = *(const bf16x8*)&vt_lds[d][(32 + g * 8) ^ fs];
      o_acc[ds] = __builtin_amdgcn_mfma_f32_16x16x32_bf16(pf0, v0, o_acc[ds], 0, 0, 0);
      o_acc[ds] = __builtin_amdgcn_mfma_f32_16x16x32_bf16(pf1, v1, o_acc[ds], 0, 0, 0);
    }
    __syncthreads();  // protect k_lds/vt_lds before next tile's staging
  }

  // ---- epilogue ----
  #pragma unroll
  for (int t = 0; t < 4; ++t) {
    const float inv = 1.0f / l_i[t];
    float* dst = Ob + (size_t)(wqb + g * 4 + t) * Dc;
    #pragma unroll
    for (int ds = 0; ds < 4; ++ds) dst[ds * 16 + r] = o_acc[ds][t] * inv;
  }
}

}  // namespace

extern "C" void kernel_launch(void* const* d_in, const int* in_sizes, int n_in,
                              void* d_out, int out_size, void* d_ws, size_t ws_size,
                              hipStream_t stream) {
  const float* q = (const float*)d_in[0];
  const float* k = (const float*)d_in[1];
  const float* v = (const float*)d_in[2];
  // d_in[3] (triu mask) applied analytically.
  float* o = (float*)d_out;
  dim3 grid(Sc / 64, Bc * Hc);
  fattn_kernel<<<grid, dim3(256), 0, stream>>>(q, k, v, o);
}

// Round 4
// 114.467 us; speedup vs baseline: 5.2137x; 2.0814x over previous
//
#include <hip/hip_runtime.h>
#include <hip/hip_bf16.h>

namespace {

constexpr int Bc = 4, Hc = 16, Sc = 2048, Dc = 64;

using bf16x2 = __attribute__((ext_vector_type(2))) __bf16;
using bf16x8 = __attribute__((ext_vector_type(8))) __bf16;
using f32x4  = __attribute__((ext_vector_type(4))) float;
using f32x16 = __attribute__((ext_vector_type(16))) float;
using uint4v = __attribute__((ext_vector_type(4))) unsigned int;

__device__ __forceinline__ float exp2_hw(float x) {
#if __has_builtin(__builtin_amdgcn_exp2f)
  return __builtin_amdgcn_exp2f(x);   // compiler-visible TRANS op: hazards handled
#else
  return exp2f(x);
#endif
}

// pack two f32 -> u32 holding 2 bf16. Compiler-visible (emits v_cvt_pk_bf16_f32
// itself) so operand order + hazards are the compiler's problem, not ours.
__device__ __forceinline__ unsigned pk_bf16(float a, float b) {
  bf16x2 t = { (__bf16)a, (__bf16)b };
  return __builtin_bit_cast(unsigned, t);
}

// v_permlane32_swap_b32 a,b: a <- [a_lo, b_lo], b <- [a_hi, b_hi].
// Raw asm bypasses the post-RA hazard recognizer -> provide gfx950 wait states
// (VALU-write->permlane-read, permlane-write->VALU-read) with s_nop padding.
// Only call with a,b = DISTINCT live values (distinct regs guaranteed).
__device__ __forceinline__ void pl32swap(unsigned& a, unsigned& b) {
  asm volatile("s_nop 1\n\tv_permlane32_swap_b32 %0, %1\n\ts_nop 1"
               : "+v"(a), "+v"(b));
}

// Cross-half pair: lo[l] = x[l&31 | low-half], hi[l] = x[l&31 | high-half].
// Round-3 bug: pl32swap(copy, copy) let the allocator put BOTH "+v" operands in
// ONE vgpr -> half-rotate instead of swap -> m/l reductions lost each lane's own
// contribution. Early-clobber explicit copies force distinct registers.
__device__ __forceinline__ void xhalf_pair(float x, float& lo, float& hi) {
  unsigned a, b;
  asm volatile("v_mov_b32 %0, %2\n\t"
               "v_mov_b32 %1, %2\n\t"
               "s_nop 1\n\t"
               "v_permlane32_swap_b32 %0, %1\n\t"
               "s_nop 1"
               : "=&v"(a), "=&v"(b)
               : "v"(x));
  lo = __builtin_bit_cast(float, a);
  hi = __builtin_bit_cast(float, b);
}
__device__ __forceinline__ float xhalf_max(float x) {
  float lo, hi; xhalf_pair(x, lo, hi); return fmaxf(lo, hi);
}
__device__ __forceinline__ float xhalf_sum(float x) {
  float lo, hi; xhalf_pair(x, lo, hi); return lo + hi;
}

__device__ __forceinline__ int vswz(int d) { return ((d >> 4) ^ d) & 7; }

// Block = 128 q-rows, 4 waves x 32 q-rows. KV tile = 64. Swapped-operand MFMA:
// S^T = mfma(K, Q)  -> lane holds P[k][q=lane&31]; in-register softmax.
// O^T = mfma(V^T, P) -> O stays in q=lane&31 layout; scalar per-lane m/l/corr.
__global__ __launch_bounds__(256, 4)
void fattn_kernel(const float* __restrict__ Q, const float* __restrict__ K,
                  const float* __restrict__ V, float* __restrict__ O) {
  const int tid  = threadIdx.x;
  const int wid  = tid >> 6;
  const int lane = tid & 63;
  const int l31  = lane & 31;
  const int hi   = lane >> 5;

  // balanced causal work: pair x-blocks (0,15),(1,14),...
  const int bx  = blockIdx.x;
  const int qxi = (bx & 1) ? (15 - (bx >> 1)) : (bx >> 1);
  const int qb  = qxi * 128;
  const int wq  = qb + wid * 32;

  const size_t base = (size_t)blockIdx.y * (Sc * Dc);
  const float* Qb = Q + base;
  const float* Kb = K + base;
  const float* Vb = V + base;
  float*       Ob = O + base;

  __shared__ __align__(16) __bf16 k_lds[64][64];   // K[k][d],  col ^= (k&7)<<3
  __shared__ __align__(16) __bf16 vt_lds[64][64];  // V^T[d][k], k ^= vswz(d)<<3

  // Q fragment (B-operand of S^T): lane holds Q[wq + l31][d = s*16 + hi*8 + j].
  // Scale = 1/sqrt(64) * log2(e) folded in (softmax runs in exp2 domain).
  constexpr float QSC = 0.125f * 1.44269504088896f;
  bf16x8 qf[4];
  {
    const float* qrow = Qb + (size_t)(wq + l31) * Dc;
    #pragma unroll
    for (int s = 0; s < 4; ++s) {
      const float* src = qrow + s * 16 + hi * 8;
      f32x4 a0 = *(const f32x4*)src;
      f32x4 a1 = *(const f32x4*)(src + 4);
      uint4v w;
      w[0] = pk_bf16(a0[0] * QSC, a0[1] * QSC);
      w[1] = pk_bf16(a0[2] * QSC, a0[3] * QSC);
      w[2] = pk_bf16(a1[0] * QSC, a1[1] * QSC);
      w[3] = pk_bf16(a1[2] * QSC, a1[3] * QSC);
      qf[s] = __builtin_bit_cast(bf16x8, w);
    }
  }

  f32x16 o0, o1;  // O^T: col q = l31; row d = dh*32 + (i&3) + 8*(i>>2) + 4*hi
  #pragma unroll
  for (int i = 0; i < 16; ++i) { o0[i] = 0.f; o1[i] = 0.f; }
  float m = -1e30f, l = 0.f;

  const int srow = tid >> 2;         // staging row 0..63
  const int scol = (tid & 3) * 16;   // staging col chunk

  const int nkb = qb / 64 + 2;
  for (int kb = 0; kb < nkb; ++kb) {
    const int kbase = kb * 64;

    // ---- cooperative staging: thread -> 16 floats of K row + 16 of V row ----
    {
      const float* ksrc = Kb + (size_t)(kbase + srow) * Dc + scol;
      f32x4 a0 = *(const f32x4*)ksrc;
      f32x4 a1 = *(const f32x4*)(ksrc + 4);
      f32x4 a2 = *(const f32x4*)(ksrc + 8);
      f32x4 a3 = *(const f32x4*)(ksrc + 12);
      uint4v w0, w1;
      w0[0] = pk_bf16(a0[0], a0[1]); w0[1] = pk_bf16(a0[2], a0[3]);
      w0[2] = pk_bf16(a1[0], a1[1]); w0[3] = pk_bf16(a1[2], a1[3]);
      w1[0] = pk_bf16(a2[0], a2[1]); w1[1] = pk_bf16(a2[2], a2[3]);
      w1[2] = pk_bf16(a3[0], a3[1]); w1[3] = pk_bf16(a3[2], a3[3]);
      const int sw = (srow & 7) << 3;
      *(uint4v*)&k_lds[srow][scol ^ sw]       = w0;
      *(uint4v*)&k_lds[srow][(scol + 8) ^ sw] = w1;

      const float* vsrc = Vb + (size_t)(kbase + srow) * Dc + scol;
      #pragma unroll
      for (int c = 0; c < 4; ++c) {
        f32x4 bv = *(const f32x4*)(vsrc + 4 * c);
        #pragma unroll
        for (int e = 0; e < 4; ++e) {
          const int d = scol + 4 * c + e;
          vt_lds[d][srow ^ (vswz(d) << 3)] = (__bf16)bv[e];
        }
      }
    }
    __syncthreads();

    if (kbase <= wq + 31) {   // wave-active (barriers stay outside this branch)
      // ---- S^T = K * Q^T : col = q (l31), rows k_local (16 regs x 2) ----
      f32x16 s0, s1;
      #pragma unroll
      for (int i = 0; i < 16; ++i) { s0[i] = 0.f; s1[i] = 0.f; }
      const int ksw = (l31 & 7) << 3;
      #pragma unroll
      for (int s = 0; s < 4; ++s) {
        bf16x8 kf = *(const bf16x8*)&k_lds[l31][(s * 16 + hi * 8) ^ ksw];
        s0 = __builtin_amdgcn_mfma_f32_32x32x16_bf16(kf, qf[s], s0, 0, 0, 0);
      }
      #pragma unroll
      for (int s = 0; s < 4; ++s) {
        bf16x8 kf = *(const bf16x8*)&k_lds[32 + l31][(s * 16 + hi * 8) ^ ksw];
        s1 = __builtin_amdgcn_mfma_f32_32x32x16_bf16(kf, qf[s], s1, 0, 0, 0);
      }

      // ---- causal mask (diagonal tiles only; wave-uniform branch) ----
      if (kbase + 63 > wq) {
        const int q   = wq + l31;
        const int dq0 = q - (kbase + 4 * hi);        // s0: k = kbase + off + 4hi
        const int dq1 = q - (kbase + 32 + 4 * hi);   // s1
        #pragma unroll
        for (int i = 0; i < 16; ++i) {
          const int off = (i & 3) + 8 * (i >> 2);
          if (off > dq0) s0[i] = -1e30f;
          if (off > dq1) s1[i] = -1e30f;
        }
      }

      // ---- in-register online softmax (exp2 domain) ----
      float pmax = s0[0];
      #pragma unroll
      for (int i = 1; i < 16; ++i) pmax = fmaxf(pmax, s0[i]);
      #pragma unroll
      for (int i = 0; i < 16; ++i) pmax = fmaxf(pmax, s1[i]);
      pmax = xhalf_max(pmax);
      const float mnew = fmaxf(m, pmax);
      const float corr = exp2_hw(m - mnew);
      m = mnew;
      #pragma unroll
      for (int i = 0; i < 16; ++i) {
        s0[i] = exp2_hw(s0[i] - mnew);
        s1[i] = exp2_hw(s1[i] - mnew);
      }
      float rs = 0.f;
      #pragma unroll
      for (int i = 0; i < 16; ++i) rs += s0[i] + s1[i];
      rs = xhalf_sum(rs);
      l = l * corr + rs;
      #pragma unroll
      for (int i = 0; i < 16; ++i) { o0[i] *= corr; o1[i] *= corr; }

      // ---- P -> PV B-fragments: 16 cvt_pk + 8 permlane32_swap, no LDS ----
      // B-frag needs P[k = 16*frag + 8*hi + j][q=l31]; we hold k = crow(i,hi).
      uint4v w;
      unsigned t0, t1, t2, t3;
      t0 = pk_bf16(s0[0], s0[1]);  t1 = pk_bf16(s0[2], s0[3]);
      t2 = pk_bf16(s0[4], s0[5]);  t3 = pk_bf16(s0[6], s0[7]);
      pl32swap(t0, t2); pl32swap(t1, t3);
      w[0] = t0; w[1] = t1; w[2] = t2; w[3] = t3;
      const bf16x8 pf0 = __builtin_bit_cast(bf16x8, w);
      t0 = pk_bf16(s0[8], s0[9]);   t1 = pk_bf16(s0[10], s0[11]);
      t2 = pk_bf16(s0[12], s0[13]); t3 = pk_bf16(s0[14], s0[15]);
      pl32swap(t0, t2); pl32swap(t1, t3);
      w[0] = t0; w[1] = t1; w[2] = t2; w[3] = t3;
      const bf16x8 pf1 = __builtin_bit_cast(bf16x8, w);
      t0 = pk_bf16(s1[0], s1[1]);  t1 = pk_bf16(s1[2], s1[3]);
      t2 = pk_bf16(s1[4], s1[5]);  t3 = pk_bf16(s1[6], s1[7]);
      pl32swap(t0, t2); pl32swap(t1, t3);
      w[0] = t0; w[1] = t1; w[2] = t2; w[3] = t3;
      const bf16x8 pf2 = __builtin_bit_cast(bf16x8, w);
      t0 = pk_bf16(s1[8], s1[9]);   t1 = pk_bf16(s1[10], s1[11]);
      t2 = pk_bf16(s1[12], s1[13]); t3 = pk_bf16(s1[14], s1[15]);
      pl32swap(t0, t2); pl32swap(t1, t3);
      w[0] = t0; w[1] = t1; w[2] = t2; w[3] = t3;
      const bf16x8 pf3 = __builtin_bit_cast(bf16x8, w);

      // ---- O^T += V^T * P : A = vt rows (d), B = P fragments ----
      const int vd0 = l31, vd1 = 32 + l31;
      const int vs0 = vswz(vd0) << 3, vs1 = vswz(vd1) << 3;
      bf16x8 vf;
      vf = *(const bf16x8*)&vt_lds[vd0][(hi * 8) ^ vs0];
      o0 = __builtin_amdgcn_mfma_f32_32x32x16_bf16(vf, pf0, o0, 0, 0, 0);
      vf = *(const bf16x8*)&vt_lds[vd0][(16 + hi * 8) ^ vs0];
      o0 = __builtin_amdgcn_mfma_f32_32x32x16_bf16(vf, pf1, o0, 0, 0, 0);
      vf = *(const bf16x8*)&vt_lds[vd0][(32 + hi * 8) ^ vs0];
      o0 = __builtin_amdgcn_mfma_f32_32x32x16_bf16(vf, pf2, o0, 0, 0, 0);
      vf = *(const bf16x8*)&vt_lds[vd0][(48 + hi * 8) ^ vs0];
      o0 = __builtin_amdgcn_mfma_f32_32x32x16_bf16(vf, pf3, o0, 0, 0, 0);
      vf = *(const bf16x8*)&vt_lds[vd1][(hi * 8) ^ vs1];
      o1 = __builtin_amdgcn_mfma_f32_32x32x16_bf16(vf, pf0, o1, 0, 0, 0);
      vf = *(const bf16x8*)&vt_lds[vd1][(16 + hi * 8) ^ vs1];
      o1 = __builtin_amdgcn_mfma_f32_32x32x16_bf16(vf, pf1, o1, 0, 0, 0);
      vf = *(const bf16x8*)&vt_lds[vd1][(32 + hi * 8) ^ vs1];
      o1 = __builtin_amdgcn_mfma_f32_32x32x16_bf16(vf, pf2, o1, 0, 0, 0);
      vf = *(const bf16x8*)&vt_lds[vd1][(48 + hi * 8) ^ vs1];
      o1 = __builtin_amdgcn_mfma_f32_32x32x16_bf16(vf, pf3, o1, 0, 0, 0);
    }
    __syncthreads();
  }

  // ---- epilogue: O^T regs -> rows of O; d = dh*32 + (i&3) + 8*(i>>2) + 4*hi ----
  const float inv = 1.0f / l;
  float* orow = Ob + (size_t)(wq + l31) * Dc;
  #pragma unroll
  for (int b = 0; b < 4; ++b) {
    f32x4 u0, u1;
    #pragma unroll
    for (int e = 0; e < 4; ++e) { u0[e] = o0[4 * b + e] * inv; u1[e] = o1[4 * b + e] * inv; }
    *(f32x4*)(orow + 8 * b + 4 * hi)      = u0;
    *(f32x4*)(orow + 32 + 8 * b + 4 * hi) = u1;
  }
}

}  // namespace

extern "C" void kernel_launch(void* const* d_in, const int* in_sizes, int n_in,
                              void* d_out, int out_size, void* d_ws, size_t ws_size,
                              hipStream_t stream) {
  const float* q = (const float*)d_in[0];
  const float* k = (const float*)d_in[1];
  const float* v = (const float*)d_in[2];
  // d_in[3] (triu mask) applied analytically.
  float* o = (float*)d_out;
  dim3 grid(Sc / 128, Bc * Hc);
  fattn_kernel<<<grid, dim3(256), 0, stream>>>(q, k, v, o);
}

// Round 5
// 71.091 us; speedup vs baseline: 8.3949x; 1.6102x over previous
//
#include <hip/hip_runtime.h>
#include <hip/hip_bf16.h>

namespace {

constexpr int Bc = 4, Hc = 16, Sc = 2048, Dc = 64;

using bf16x2 = __attribute__((ext_vector_type(2))) __bf16;
using bf16x8 = __attribute__((ext_vector_type(8))) __bf16;
using f32x4  = __attribute__((ext_vector_type(4))) float;
using f32x16 = __attribute__((ext_vector_type(16))) float;
using uint4v = __attribute__((ext_vector_type(4))) unsigned int;

__device__ __forceinline__ float exp2_hw(float x) {
#if __has_builtin(__builtin_amdgcn_exp2f)
  return __builtin_amdgcn_exp2f(x);
#else
  return exp2f(x);
#endif
}

__device__ __forceinline__ unsigned pk_bf16(float a, float b) {
  bf16x2 t = { (__bf16)a, (__bf16)b };
  return __builtin_bit_cast(unsigned, t);
}

// v_permlane32_swap_b32 a,b with s_nop hazard padding (raw asm bypasses the
// post-RA hazard recognizer). Operands must be DISTINCT live values.
__device__ __forceinline__ void pl32swap(unsigned& a, unsigned& b) {
  asm volatile("s_nop 1\n\tv_permlane32_swap_b32 %0, %1\n\ts_nop 1"
               : "+v"(a), "+v"(b));
}
// Early-clobber dual-mov guarantees the two swap operands sit in distinct regs
// (round-3 lesson: copies of one SSA value may share a VGPR).
__device__ __forceinline__ void xhalf_pair(float x, float& lo, float& hi) {
  unsigned a, b;
  asm volatile("v_mov_b32 %0, %2\n\t"
               "v_mov_b32 %1, %2\n\t"
               "s_nop 1\n\t"
               "v_permlane32_swap_b32 %0, %1\n\t"
               "s_nop 1"
               : "=&v"(a), "=&v"(b)
               : "v"(x));
  lo = __builtin_bit_cast(float, a);
  hi = __builtin_bit_cast(float, b);
}
__device__ __forceinline__ float xhalf_max(float x) {
  float lo, hi; xhalf_pair(x, lo, hi); return fmaxf(lo, hi);
}
__device__ __forceinline__ float xhalf_sum(float x) {
  float lo, hi; xhalf_pair(x, lo, hi); return lo + hi;
}

__device__ __forceinline__ int vswz(int d) { return ((d >> 4) ^ d) & 7; }

// Block = 4 waves x 32 q-rows = 128-row q-panel; each block processes the
// panel PAIR {p, 15-p} sequentially -> exactly 34 KV-tiles per block (perfect
// causal balance; grid 8x64 = 512 blocks, 2/CU, flat residency).
// Double-buffered KV LDS + async-split staging: issue tile t+1 global loads
// before computing tile t; vmcnt-wait + LDS write after compute.
__global__ __launch_bounds__(256, 2)
void fattn_kernel(const float* __restrict__ Q, const float* __restrict__ K,
                  const float* __restrict__ V, float* __restrict__ O) {
  const int tid  = threadIdx.x;
  const int wid  = tid >> 6;
  const int lane = tid & 63;
  const int l31  = lane & 31;
  const int hi   = lane >> 5;

  // XCD-bijective swizzle (512 = 8 XCD x 64): XCD x owns bh in [8x, 8x+8).
  const int flat = blockIdx.x + 8 * blockIdx.y;
  const int w    = (flat & 7) * 64 + (flat >> 3);
  const int p    = w & 7;
  const int bh   = w >> 3;

  const size_t base = (size_t)bh * (Sc * Dc);
  const float* Qb = Q + base;
  const float* Kb = K + base;
  const float* Vb = V + base;
  float*       Ob = O + base;

  __shared__ __align__(16) __bf16 k_lds[2][64][64];   // K[k][d],  col ^= (k&7)<<3
  __shared__ __align__(16) __bf16 vt_lds[2][64][64];  // V^T[d][k], k ^= vswz(d)<<3

  const int srow = tid >> 2;         // staging row 0..63
  const int scol = (tid & 3) * 16;   // staging col chunk
  const int ssw  = (srow & 7) << 3;

  constexpr float QSC = 0.125f * 1.44269504088896f;  // 1/sqrt(D) * log2(e)

  for (int half = 0; half < 2; ++half) {
    const int qp = half ? (15 - p) : p;
    const int qb = qp * 128;
    const int wq = qb + wid * 32;
    const int nkb = 2 * qp + 2;

    // ---- Q fragment: lane holds Q[wq + l31][d = s*16 + hi*8 + j] ----
    bf16x8 qf[4];
    {
      const float* qrow = Qb + (size_t)(wq + l31) * Dc;
      #pragma unroll
      for (int s = 0; s < 4; ++s) {
        const float* src = qrow + s * 16 + hi * 8;
        f32x4 a0 = *(const f32x4*)src;
        f32x4 a1 = *(const f32x4*)(src + 4);
        uint4v wv;
        wv[0] = pk_bf16(a0[0] * QSC, a0[1] * QSC);
        wv[1] = pk_bf16(a0[2] * QSC, a0[3] * QSC);
        wv[2] = pk_bf16(a1[0] * QSC, a1[1] * QSC);
        wv[3] = pk_bf16(a1[2] * QSC, a1[3] * QSC);
        qf[s] = __builtin_bit_cast(bf16x8, wv);
      }
    }

    f32x16 o0, o1;   // O^T: col q = l31; row d = dh*32 + (i&3) + 8*(i>>2) + 4*hi
    #pragma unroll
    for (int i = 0; i < 16; ++i) { o0[i] = 0.f; o1[i] = 0.f; }
    float m = -1e30f, l = 0.f;

    // ---- prologue: stage tile 0 into buffer 0 ----
    {
      const float* ksrc = Kb + (size_t)srow * Dc + scol;
      f32x4 a0 = *(const f32x4*)ksrc;
      f32x4 a1 = *(const f32x4*)(ksrc + 4);
      f32x4 a2 = *(const f32x4*)(ksrc + 8);
      f32x4 a3 = *(const f32x4*)(ksrc + 12);
      const float* vsrc = Vb + (size_t)srow * Dc + scol;
      f32x4 b0 = *(const f32x4*)vsrc;
      f32x4 b1 = *(const f32x4*)(vsrc + 4);
      f32x4 b2 = *(const f32x4*)(vsrc + 8);
      f32x4 b3 = *(const f32x4*)(vsrc + 12);
      uint4v w0, w1;
      w0[0] = pk_bf16(a0[0], a0[1]); w0[1] = pk_bf16(a0[2], a0[3]);
      w0[2] = pk_bf16(a1[0], a1[1]); w0[3] = pk_bf16(a1[2], a1[3]);
      w1[0] = pk_bf16(a2[0], a2[1]); w1[1] = pk_bf16(a2[2], a2[3]);
      w1[2] = pk_bf16(a3[0], a3[1]); w1[3] = pk_bf16(a3[2], a3[3]);
      *(uint4v*)&k_lds[0][srow][scol ^ ssw]       = w0;
      *(uint4v*)&k_lds[0][srow][(scol + 8) ^ ssw] = w1;
      f32x4 bb[4] = { b0, b1, b2, b3 };
      #pragma unroll
      for (int c = 0; c < 4; ++c)
        #pragma unroll
        for (int e = 0; e < 4; ++e) {
          const int d = scol + 4 * c + e;
          vt_lds[0][d][srow ^ (vswz(d) << 3)] = (__bf16)bb[c][e];
        }
    }
    __syncthreads();

    for (int t = 0; t < nkb; ++t) {
      const int cur   = t & 1;
      const int kbase = t * 64;
      const bool pre  = (t + 1 < nkb);

      // ---- issue next tile's global loads EARLY (in flight during compute) ----
      f32x4 a0, a1, a2, a3, b0, b1, b2, b3;
      if (pre) {
        const float* ksrc = Kb + (size_t)(kbase + 64 + srow) * Dc + scol;
        a0 = *(const f32x4*)ksrc;
        a1 = *(const f32x4*)(ksrc + 4);
        a2 = *(const f32x4*)(ksrc + 8);
        a3 = *(const f32x4*)(ksrc + 12);
        const float* vsrc = Vb + (size_t)(kbase + 64 + srow) * Dc + scol;
        b0 = *(const f32x4*)vsrc;
        b1 = *(const f32x4*)(vsrc + 4);
        b2 = *(const f32x4*)(vsrc + 8);
        b3 = *(const f32x4*)(vsrc + 12);
      }

      if (kbase <= wq + 31) {   // wave-active (no barriers inside)
        const __bf16 (*kc)[64] = k_lds[cur];
        const __bf16 (*vc)[64] = vt_lds[cur];

        // ---- S^T = K * Q^T ----
        f32x16 s0, s1;
        #pragma unroll
        for (int i = 0; i < 16; ++i) { s0[i] = 0.f; s1[i] = 0.f; }
        const int ksw = (l31 & 7) << 3;
        #pragma unroll
        for (int s = 0; s < 4; ++s) {
          bf16x8 kf = *(const bf16x8*)&kc[l31][(s * 16 + hi * 8) ^ ksw];
          s0 = __builtin_amdgcn_mfma_f32_32x32x16_bf16(kf, qf[s], s0, 0, 0, 0);
        }
        #pragma unroll
        for (int s = 0; s < 4; ++s) {
          bf16x8 kf = *(const bf16x8*)&kc[32 + l31][(s * 16 + hi * 8) ^ ksw];
          s1 = __builtin_amdgcn_mfma_f32_32x32x16_bf16(kf, qf[s], s1, 0, 0, 0);
        }

        // ---- causal mask (diagonal tiles only) ----
        if (kbase + 63 > wq) {
          const int q   = wq + l31;
          const int dq0 = q - (kbase + 4 * hi);
          const int dq1 = q - (kbase + 32 + 4 * hi);
          #pragma unroll
          for (int i = 0; i < 16; ++i) {
            const int off = (i & 3) + 8 * (i >> 2);
            if (off > dq0) s0[i] = -1e30f;
            if (off > dq1) s1[i] = -1e30f;
          }
        }

        // ---- in-register online softmax (exp2 domain) ----
        float pmax = s0[0];
        #pragma unroll
        for (int i = 1; i < 16; ++i) pmax = fmaxf(pmax, s0[i]);
        #pragma unroll
        for (int i = 0; i < 16; ++i) pmax = fmaxf(pmax, s1[i]);
        pmax = xhalf_max(pmax);
        const float mnew = fmaxf(m, pmax);
        const float corr = exp2_hw(m - mnew);
        m = mnew;
        #pragma unroll
        for (int i = 0; i < 16; ++i) {
          s0[i] = exp2_hw(s0[i] - mnew);
          s1[i] = exp2_hw(s1[i] - mnew);
        }
        float rs = 0.f;
        #pragma unroll
        for (int i = 0; i < 16; ++i) rs += s0[i] + s1[i];
        rs = xhalf_sum(rs);
        l = l * corr + rs;
        #pragma unroll
        for (int i = 0; i < 16; ++i) { o0[i] *= corr; o1[i] *= corr; }

        // ---- P -> PV B-fragments: 16 cvt_pk + 8 permlane32_swap ----
        uint4v wv;
        unsigned t0, t1, t2, t3;
        t0 = pk_bf16(s0[0], s0[1]);  t1 = pk_bf16(s0[2], s0[3]);
        t2 = pk_bf16(s0[4], s0[5]);  t3 = pk_bf16(s0[6], s0[7]);
        pl32swap(t0, t2); pl32swap(t1, t3);
        wv[0] = t0; wv[1] = t1; wv[2] = t2; wv[3] = t3;
        const bf16x8 pf0 = __builtin_bit_cast(bf16x8, wv);
        t0 = pk_bf16(s0[8], s0[9]);   t1 = pk_bf16(s0[10], s0[11]);
        t2 = pk_bf16(s0[12], s0[13]); t3 = pk_bf16(s0[14], s0[15]);
        pl32swap(t0, t2); pl32swap(t1, t3);
        wv[0] = t0; wv[1] = t1; wv[2] = t2; wv[3] = t3;
        const bf16x8 pf1 = __builtin_bit_cast(bf16x8, wv);
        t0 = pk_bf16(s1[0], s1[1]);  t1 = pk_bf16(s1[2], s1[3]);
        t2 = pk_bf16(s1[4], s1[5]);  t3 = pk_bf16(s1[6], s1[7]);
        pl32swap(t0, t2); pl32swap(t1, t3);
        wv[0] = t0; wv[1] = t1; wv[2] = t2; wv[3] = t3;
        const bf16x8 pf2 = __builtin_bit_cast(bf16x8, wv);
        t0 = pk_bf16(s1[8], s1[9]);   t1 = pk_bf16(s1[10], s1[11]);
        t2 = pk_bf16(s1[12], s1[13]); t3 = pk_bf16(s1[14], s1[15]);
        pl32swap(t0, t2); pl32swap(t1, t3);
        wv[0] = t0; wv[1] = t1; wv[2] = t2; wv[3] = t3;
        const bf16x8 pf3 = __builtin_bit_cast(bf16x8, wv);

        // ---- O^T += V^T * P ----
        const int vd0 = l31, vd1 = 32 + l31;
        const int vs0 = vswz(vd0) << 3, vs1 = vswz(vd1) << 3;
        bf16x8 vf;
        vf = *(const bf16x8*)&vc[vd0][(hi * 8) ^ vs0];
        o0 = __builtin_amdgcn_mfma_f32_32x32x16_bf16(vf, pf0, o0, 0, 0, 0);
        vf = *(const bf16x8*)&vc[vd0][(16 + hi * 8) ^ vs0];
        o0 = __builtin_amdgcn_mfma_f32_32x32x16_bf16(vf, pf1, o0, 0, 0, 0);
        vf = *(const bf16x8*)&vc[vd0][(32 + hi * 8) ^ vs0];
        o0 = __builtin_amdgcn_mfma_f32_32x32x16_bf16(vf, pf2, o0, 0, 0, 0);
        vf = *(const bf16x8*)&vc[vd0][(48 + hi * 8) ^ vs0];
        o0 = __builtin_amdgcn_mfma_f32_32x32x16_bf16(vf, pf3, o0, 0, 0, 0);
        vf = *(const bf16x8*)&vc[vd1][(hi * 8) ^ vs1];
        o1 = __builtin_amdgcn_mfma_f32_32x32x16_bf16(vf, pf0, o1, 0, 0, 0);
        vf = *(const bf16x8*)&vc[vd1][(16 + hi * 8) ^ vs1];
        o1 = __builtin_amdgcn_mfma_f32_32x32x16_bf16(vf, pf1, o1, 0, 0, 0);
        vf = *(const bf16x8*)&vc[vd1][(32 + hi * 8) ^ vs1];
        o1 = __builtin_amdgcn_mfma_f32_32x32x16_bf16(vf, pf2, o1, 0, 0, 0);
        vf = *(const bf16x8*)&vc[vd1][(48 + hi * 8) ^ vs1];
        o1 = __builtin_amdgcn_mfma_f32_32x32x16_bf16(vf, pf3, o1, 0, 0, 0);
      }

      // ---- STAGE_WRITE for t+1 (vmcnt wait lands here, after compute) ----
      if (pre) {
        const int nxt = cur ^ 1;
        uint4v w0, w1;
        w0[0] = pk_bf16(a0[0], a0[1]); w0[1] = pk_bf16(a0[2], a0[3]);
        w0[2] = pk_bf16(a1[0], a1[1]); w0[3] = pk_bf16(a1[2], a1[3]);
        w1[0] = pk_bf16(a2[0], a2[1]); w1[1] = pk_bf16(a2[2], a2[3]);
        w1[2] = pk_bf16(a3[0], a3[1]); w1[3] = pk_bf16(a3[2], a3[3]);
        *(uint4v*)&k_lds[nxt][srow][scol ^ ssw]       = w0;
        *(uint4v*)&k_lds[nxt][srow][(scol + 8) ^ ssw] = w1;
        f32x4 bb[4] = { b0, b1, b2, b3 };
        #pragma unroll
        for (int c = 0; c < 4; ++c)
          #pragma unroll
          for (int e = 0; e < 4; ++e) {
            const int d = scol + 4 * c + e;
            vt_lds[nxt][d][srow ^ (vswz(d) << 3)] = (__bf16)bb[c][e];
          }
      }
      __syncthreads();
    }

    // ---- epilogue: O^T regs -> rows of O ----
    const float inv = 1.0f / l;
    float* orow = Ob + (size_t)(wq + l31) * Dc;
    #pragma unroll
    for (int b = 0; b < 4; ++b) {
      f32x4 u0, u1;
      #pragma unroll
      for (int e = 0; e < 4; ++e) { u0[e] = o0[4 * b + e] * inv; u1[e] = o1[4 * b + e] * inv; }
      *(f32x4*)(orow + 8 * b + 4 * hi)      = u0;
      *(f32x4*)(orow + 32 + 8 * b + 4 * hi) = u1;
    }
    __syncthreads();  // LDS reuse guard before next panel's prologue
  }
}

}  // namespace

extern "C" void kernel_launch(void* const* d_in, const int* in_sizes, int n_in,
                              void* d_out, int out_size, void* d_ws, size_t ws_size,
                              hipStream_t stream) {
  const float* q = (const float*)d_in[0];
  const float* k = (const float*)d_in[1];
  const float* v = (const float*)d_in[2];
  // d_in[3] (triu mask) applied analytically.
  float* o = (float*)d_out;
  dim3 grid(8, Bc * Hc);
  fattn_kernel<<<grid, dim3(256), 0, stream>>>(q, k, v, o);
}